// Round 8
// baseline (8813.565 us; speedup 1.0000x reference)
//
#include <hip/hip_runtime.h>
#include <math.h>

#define BSZ 32
#define TT  32
#define XD  128
#define HD  512
#define VT  2048
#define ET  463
#define GKS 8
#define VKS 16

__device__ __forceinline__ float sigf(float x){ return 1.f/(1.f+expf(-x)); }
__device__ __forceinline__ float logsigf(float x){
    return (x >= 0.f) ? -log1pf(expf(-x)) : x - log1pf(expf(x));
}

// ---- 1024-thread block reductions (wave shfl + 16 partials; red[17+]) --------------
__device__ __forceinline__ float bsum(float v, float* red, int tid){
    #pragma unroll
    for (int off = 32; off > 0; off >>= 1) v += __shfl_xor(v, off);
    if ((tid & 63) == 0) red[tid >> 6] = v;
    __syncthreads();
    if (tid == 0){
        float s = red[0];
        #pragma unroll
        for (int i = 1; i < 16; ++i) s += red[i];
        red[16] = s;
    }
    __syncthreads();
    float r = red[16];
    __syncthreads();
    return r;
}
__device__ __forceinline__ float bmax(float v, float* red, int tid){
    #pragma unroll
    for (int off = 32; off > 0; off >>= 1) v = fmaxf(v, __shfl_xor(v, off));
    if ((tid & 63) == 0) red[tid >> 6] = v;
    __syncthreads();
    if (tid == 0){
        float s = red[0];
        #pragma unroll
        for (int i = 1; i < 16; ++i) s = fmaxf(s, red[i]);
        red[16] = s;
    }
    __syncthreads();
    float r = red[16];
    __syncthreads();
    return r;
}

// ---------------- batchnorm of x for ALL timesteps (recurrence-independent) ---------
__global__ void dnc_bnx(const float* __restrict__ x, float* __restrict__ bnx){
    int t = blockIdx.x, k = threadIdx.x;   // 128 threads
    float vals[BSZ];
    float s = 0.f;
    #pragma unroll
    for (int b = 0; b < BSZ; ++b){ vals[b] = x[(b*TT + t)*XD + k]; s += vals[b]; }
    float mean = s * (1.f/BSZ);
    float ss = 0.f;
    #pragma unroll
    for (int b = 0; b < BSZ; ++b){ float d = vals[b]-mean; ss += d*d; }
    float inv = 1.f / sqrtf(ss*(1.f/BSZ) + 1e-5f);
    #pragma unroll
    for (int b = 0; b < BSZ; ++b) bnx[((size_t)t*BSZ + b)*XD + k] = (vals[b]-mean)*inv;
}

// ---------------- LSTM pre-activation GEMM, 3-source (A | B | h), k-split -----------
// grid (16 jchunks, 2 dirs, GKS), block 256. thread: 4 j x 4 b accumulators.
// 8 FMA/lane per ds_read_b128; weights direct from global as float4.
__global__ void dnc_lstm_gemm(const float* __restrict__ srcA, int KA,
                              const float* __restrict__ srcB, int KB,
                              const float* __restrict__ hbase,
                              const float* __restrict__ Wih, const float* __restrict__ Whh,
                              float* __restrict__ gpart){
    const int jc = blockIdx.x, d = blockIdx.y, ks = blockIdx.z;
    const int tid = threadIdx.x;
    const int jg = tid & 31, bg = tid >> 5;
    const int j0 = jc*128 + jg*4;
    const int b0 = bg*4;
    const int K1 = KA + KB;
    const int cA = KA >> 6;
    const int cin = K1 >> 6;
    const int nct = cin + 8;               // + HD/64 h-chunks
    const int per = (nct + GKS - 1) / GKS;
    int c0 = ks*per; int c1 = min(nct, c0+per);
    __shared__ __align__(16) float tile[64*36];
    float acc[4][4] = {{0}};
    for (int c = c0; c < c1; ++c){
        const float* src; int stride, kb, wcol; const float* Wb; int Kw;
        if (c < cA){ src = srcA; stride = KA; kb = c*64; wcol = c*64;
                     Wb = Wih + (size_t)d*2048*K1; Kw = K1; }
        else if (c < cin){ src = srcB; stride = KB; kb = (c-cA)*64; wcol = c*64;
                           Wb = Wih + (size_t)d*2048*K1; Kw = K1; }
        else { src = hbase + d*(BSZ*HD); stride = HD; kb = (c-cin)*64; wcol = kb;
               Wb = Whh + (size_t)d*2048*512; Kw = 512; }
        #pragma unroll
        for (int i = 0; i < 8; ++i){
            int idx = i*256 + tid; int kk = idx & 63, b = idx >> 6;
            tile[kk*36 + b] = src[b*stride + kb + kk];
        }
        __syncthreads();
        const float* w0p = Wb + (size_t)(j0+0)*Kw + wcol;
        const float* w1p = Wb + (size_t)(j0+1)*Kw + wcol;
        const float* w2p = Wb + (size_t)(j0+2)*Kw + wcol;
        const float* w3p = Wb + (size_t)(j0+3)*Kw + wcol;
        #pragma unroll
        for (int kk = 0; kk < 64; kk += 4){
            float4 a0 = *(const float4*)&tile[(kk+0)*36 + b0];
            float4 a1 = *(const float4*)&tile[(kk+1)*36 + b0];
            float4 a2 = *(const float4*)&tile[(kk+2)*36 + b0];
            float4 a3 = *(const float4*)&tile[(kk+3)*36 + b0];
            float4 w;
            #define ACCJ(JJ, WP) \
                w = *(const float4*)(WP + kk); \
                acc[JJ][0] += a0.x*w.x + a1.x*w.y + a2.x*w.z + a3.x*w.w; \
                acc[JJ][1] += a0.y*w.x + a1.y*w.y + a2.y*w.z + a3.y*w.w; \
                acc[JJ][2] += a0.z*w.x + a1.z*w.y + a2.z*w.z + a3.z*w.w; \
                acc[JJ][3] += a0.w*w.x + a1.w*w.y + a2.w*w.z + a3.w*w.w;
            ACCJ(0, w0p) ACCJ(1, w1p) ACCJ(2, w2p) ACCJ(3, w3p)
            #undef ACCJ
        }
        __syncthreads();
    }
    #pragma unroll
    for (int jj = 0; jj < 4; ++jj){
        #pragma unroll
        for (int bb = 0; bb < 4; ++bb)
            gpart[((size_t)(d*GKS + ks)*BSZ + (b0+bb))*2048 + (j0+jj)] = acc[jj][bb];
    }
}

// ---------------- LSTM gates: sum partials -> h, c, flat, optional next input --------
__global__ void dnc_gates(const float* __restrict__ gpart,
                          const float* __restrict__ bih, const float* __restrict__ bhh,
                          float* __restrict__ cstate, float* __restrict__ hwrite,
                          float* __restrict__ flat, float* __restrict__ lout, int l){
    int idx = blockIdx.x*256 + threadIdx.x;
    int u = idx & 511, b = (idx >> 9) & 31, d = idx >> 14;
    int cell = 2*l + d;
    float g[4];
    #pragma unroll
    for (int xg = 0; xg < 4; ++xg){
        int j = xg*512 + u;
        float s = bih[d*2048 + j] + bhh[d*2048 + j];
        #pragma unroll
        for (int ks = 0; ks < GKS; ++ks)
            s += gpart[((size_t)(d*GKS + ks)*BSZ + b)*2048 + j];
        g[xg] = s;
    }
    float ig = sigf(g[0]), fg = sigf(g[1]), og = sigf(g[3]);
    float gg = tanhf(g[2]);
    int ci = (cell*BSZ + b)*HD + u;
    float c2 = fg*cstate[ci] + ig*gg;
    cstate[ci] = c2;
    float h = og*tanhf(c2);
    hwrite[ci] = h;
    flat[b*2048 + cell*HD + u] = h;
    if (lout) lout[b*1024 + d*HD + u] = h;
}

// ---------------- combined GEMV: flat@Wy (bx 0-7, float4 weights) + flat@WE (bx 8-11) -
__global__ void dnc_gemv2(const float* __restrict__ fin, const float* __restrict__ Wy,
                          const float* __restrict__ WE,
                          float* __restrict__ vtp, float* __restrict__ ep){
    const int bx = blockIdx.x, ksi = blockIdx.y;
    const int tid = threadIdx.x;
    const int lane = tid & 63, bg = tid >> 6;
    const int b0 = bg*8;
    const int k0 = ksi*128;
    __shared__ __align__(16) float tile[128*36];
    #pragma unroll
    for (int i = 0; i < 16; ++i){
        int idx = i*256 + tid; int kk = idx & 127, b = idx >> 7;
        tile[kk*36 + b] = fin[b*2048 + k0 + kk];
    }
    __syncthreads();

    if (bx < 8){
        // ---- Wy path: lane owns 4 consecutive m; float4 weight loads ----
        const int m = bx*256 + lane*4;
        float acc[8][4] = {{0}};
        #pragma unroll 4
        for (int kk = 0; kk < 128; ++kk){
            float4 w  = *(const float4*)&Wy[(size_t)(k0+kk)*VT + m];
            float4 a0 = *(const float4*)&tile[kk*36 + b0];
            float4 a1 = *(const float4*)&tile[kk*36 + b0 + 4];
            acc[0][0]+=a0.x*w.x; acc[0][1]+=a0.x*w.y; acc[0][2]+=a0.x*w.z; acc[0][3]+=a0.x*w.w;
            acc[1][0]+=a0.y*w.x; acc[1][1]+=a0.y*w.y; acc[1][2]+=a0.y*w.z; acc[1][3]+=a0.y*w.w;
            acc[2][0]+=a0.z*w.x; acc[2][1]+=a0.z*w.y; acc[2][2]+=a0.z*w.z; acc[2][3]+=a0.z*w.w;
            acc[3][0]+=a0.w*w.x; acc[3][1]+=a0.w*w.y; acc[3][2]+=a0.w*w.z; acc[3][3]+=a0.w*w.w;
            acc[4][0]+=a1.x*w.x; acc[4][1]+=a1.x*w.y; acc[4][2]+=a1.x*w.z; acc[4][3]+=a1.x*w.w;
            acc[5][0]+=a1.y*w.x; acc[5][1]+=a1.y*w.y; acc[5][2]+=a1.y*w.z; acc[5][3]+=a1.y*w.w;
            acc[6][0]+=a1.z*w.x; acc[6][1]+=a1.z*w.y; acc[6][2]+=a1.z*w.z; acc[6][3]+=a1.z*w.w;
            acc[7][0]+=a1.w*w.x; acc[7][1]+=a1.w*w.y; acc[7][2]+=a1.w*w.z; acc[7][3]+=a1.w*w.w;
        }
        #pragma unroll
        for (int bb = 0; bb < 8; ++bb){
            float4 st = make_float4(acc[bb][0], acc[bb][1], acc[bb][2], acc[bb][3]);
            *(float4*)&vtp[((size_t)ksi*BSZ + b0+bb)*VT + m] = st;
        }
    } else {
        // ---- WE path (Mdim 463 odd -> scalar weights, 2 m per thread) ----
        const int mb = bx - 8;
        const int m0 = mb*128 + lane, m1 = m0 + 64;
        bool v0 = m0 < ET, v1 = m1 < ET;
        float acc[16] = {0};
        #pragma unroll 2
        for (int kk = 0; kk < 128; ++kk){
            float4 pq = *(const float4*)&tile[kk*36 + b0];
            float4 qq = *(const float4*)&tile[kk*36 + b0 + 4];
            const float* wr = WE + (size_t)(k0+kk)*ET;
            float w0 = v0 ? wr[m0] : 0.f;
            float w1 = v1 ? wr[m1] : 0.f;
            acc[0]+=pq.x*w0; acc[1]+=pq.y*w0; acc[2]+=pq.z*w0; acc[3]+=pq.w*w0;
            acc[4]+=qq.x*w0; acc[5]+=qq.y*w0; acc[6]+=qq.z*w0; acc[7]+=qq.w*w0;
            acc[8]+=pq.x*w1; acc[9]+=pq.y*w1; acc[10]+=pq.z*w1; acc[11]+=pq.w*w1;
            acc[12]+=qq.x*w1; acc[13]+=qq.y*w1; acc[14]+=qq.z*w1; acc[15]+=qq.w*w1;
        }
        if (v0){
            #pragma unroll
            for (int bb = 0; bb < 8; ++bb)
                ep[((size_t)ksi*BSZ + b0+bb)*ET + m0] = acc[bb];
        }
        if (v1){
            #pragma unroll
            for (int bb = 0; bb < 8; ++bb)
                ep[((size_t)ksi*BSZ + b0+bb)*ET + m1] = acc[8+bb];
        }
    }
}

// ---------------- presort (blocks 0-31) || cw_score (blocks 32-63) -------------------
__global__ __launch_bounds__(1024) void dnc_presort_cw(
    const float* __restrict__ ep, const float* __restrict__ lrw,
    const float* __restrict__ lww, float* __restrict__ ubuf,
    float* __restrict__ iv, float* __restrict__ allocw,
    const float* __restrict__ M, float* __restrict__ scw)
{
    const int bid = blockIdx.x, tid = threadIdx.x;
    const int lane = tid & 63, wid = tid >> 6;
    __shared__ float red[32];
    __shared__ float ivS[464];
    __shared__ unsigned long long keysS[1024];
    __shared__ float wtot[16], wpref[16];

    if (bid < 32){
        const int b = bid;
        // layernorm of WE partial sums -> iv
        float myv = 0.f;
        if (tid < ET){
            #pragma unroll
            for (int s = 0; s < VKS; ++s) myv += ep[((size_t)s*BSZ + b)*ET + tid];
        }
        float mean = bsum(myv, red, tid) * (1.f/ET);
        float dd = (tid < ET) ? (myv - mean) : 0.f;
        float var = bsum(dd*dd, red, tid) * (1.f/ET);
        float rinv = 1.f / sqrtf(var + 1e-5f);
        float ivv = (myv - mean)*rinv;
        if (tid < ET){ ivS[tid] = ivv; iv[b*ET + tid] = ivv; }
        __syncthreads();

        // usage
        const int n = tid;
        float4 lw4 = *(const float4*)&lrw[((size_t)b*1024 + n)*4];
        float f0 = sigf(ivS[453]), f1 = sigf(ivS[454]), f2 = sigf(ivS[455]), f3 = sigf(ivS[456]);
        float ret = (1.f-f0*lw4.x)*(1.f-f1*lw4.y)*(1.f-f2*lw4.z)*(1.f-f3*lw4.w);
        float uo = ubuf[b*1024+n], lwo = lww[b*1024+n];
        float un = (uo + lwo - uo*lwo)*ret;
        ubuf[b*1024+n] = un;

        // hybrid bitonic sort (LDS j>=64, shfl j<64); u>=0 so uint order == float order
        unsigned long long key = ((unsigned long long)__float_as_uint(un) << 32) | (unsigned)tid;
        for (int k = 2; k <= 1024; k <<= 1){
            int j = k >> 1;
            for (; j >= 64; j >>= 1){
                keysS[tid] = key; __syncthreads();
                unsigned long long other = keysS[tid ^ j];
                bool up = ((tid & k) == 0);
                bool takeMin = (((tid & j) == 0) == up);
                key = takeMin ? (key < other ? key : other) : (key > other ? key : other);
                __syncthreads();
            }
            for (; j >= 1; j >>= 1){
                unsigned long long other = __shfl_xor(key, j);
                bool up = ((tid & k) == 0);
                bool takeMin = (((tid & j) == 0) == up);
                key = takeMin ? (key < other ? key : other) : (key > other ? key : other);
            }
        }
        float su = __uint_as_float((unsigned)(key >> 32));
        int idxv = (int)(key & 0xffffffffu);

        // exclusive cumprod via wave shfl scan + 16 wave totals
        float p = su;
        #pragma unroll
        for (int o = 1; o < 64; o <<= 1){ float q = __shfl_up(p, o); if (lane >= o) p *= q; }
        if (lane == 63) wtot[wid] = p;
        __syncthreads();
        if (tid == 0){
            float r = 1.f;
            #pragma unroll
            for (int i = 0; i < 16; ++i){ wpref[i] = r; r *= wtot[i]; }
        }
        __syncthreads();
        float excl = __shfl_up(p, 1); if (lane == 0) excl = 1.f;
        float cpx = excl * wpref[wid];
        allocw[b*1024 + idxv] = (1.f - su)*cpx;
    } else {
        const int b = bid - 32;
        // mini-layernorm recompute (cheap; breaks same-stage dependency on iv)
        float myv = 0.f;
        if (tid < ET){
            #pragma unroll
            for (int s = 0; s < VKS; ++s) myv += ep[((size_t)s*BSZ + b)*ET + tid];
        }
        float mean = bsum(myv, red, tid) * (1.f/ET);
        float dd = (tid < ET) ? (myv - mean) : 0.f;
        float var = bsum(dd*dd, red, tid) * (1.f/ET);
        float rinv = 1.f / sqrtf(var + 1e-5f);
        float ivv = (myv - mean)*rinv;
        if (tid >= 260 && tid < 324) ivS[tid - 260] = ivv;   // write key
        if (tid == 324) ivS[64] = 1.f - logsigf(ivv);        // wbeta
        __syncthreads();
        float ksq = 0.f;
        #pragma unroll
        for (int w = 0; w < 64; ++w) ksq += ivS[w]*ivS[w];
        float kden = sqrtf(ksq) + 1e-8f;
        float wb = ivS[64];
        const float* Mrow = M + ((size_t)b*1024 + tid)*64;
        float dot = 0.f, msq = 0.f;
        #pragma unroll
        for (int w = 0; w < 64; w += 4){
            float4 mv = *(const float4*)(Mrow + w);
            dot += mv.x*ivS[w] + mv.y*ivS[w+1] + mv.z*ivS[w+2] + mv.w*ivS[w+3];
            msq += mv.x*mv.x + mv.y*mv.y + mv.z*mv.z + mv.w*mv.w;
        }
        scw[b*1024 + tid] = wb*dot/((sqrtf(msq) + 1e-8f)*kden);
    }
}

// ------- fused memory tail (32 blks x 1024): cw-softmax+ww, M update, read scores,
//         read softmax, read vectors. scr lives in LDS; M re-read via same-CU L1/L2. --
__global__ __launch_bounds__(1024) void dnc_memup_rv(
    float* __restrict__ M, const float* __restrict__ scw,
    const float* __restrict__ allocw, const float* __restrict__ iv,
    float* __restrict__ lww, float* __restrict__ lrw, float* __restrict__ lrv)
{
    const int b = blockIdx.x, tid = threadIdx.x;
    const int lane = tid & 63, wid = tid >> 6;
    __shared__ float red[32];
    __shared__ float aux[400];
    __shared__ float pS[4096];     // [r][n] scores then rw
    __shared__ float rvS[1024];
    const int n = tid;

    // ---- content-write softmax + ww ----
    float s = scw[b*1024 + n];
    float mx = bmax(s, red, tid);
    float tot = bsum(expf(s - mx), red, tid);
    float cwv = expf(s - mx)/tot;
    float ag = sigf(iv[b*ET + 457]), wg = sigf(iv[b*ET + 458]);
    float wwv = wg*(ag*allocw[b*1024 + n] + (1.f-ag)*cwv);
    lww[b*1024 + n] = wwv;

    // stage erase[0..63], wvec[64..127], rkn[128..383], nrm[384..387], rb[392..395]
    if (tid < 64){ aux[tid] = sigf(iv[b*ET + 325 + tid]); aux[64+tid] = iv[b*ET + 389 + tid]; }
    if (tid >= 64 && tid < 320) aux[64 + tid] = iv[b*ET + (tid - 64)];
    if (tid >= 320 && tid < 324) aux[72 + tid] = 1.f - logsigf(iv[b*ET + 256 + (tid - 320)]);
    __syncthreads();
    if (tid < 4){
        float ss = 0.f;
        #pragma unroll
        for (int w = 0; w < 64; ++w){ float v = aux[128 + w*4 + tid]; ss += v*v; }
        aux[384 + tid] = sqrtf(ss) + 1e-8f;
    }
    __syncthreads();
    if (tid < 256) aux[128 + tid] = aux[128 + tid] / aux[384 + (tid & 3)];
    __syncthreads();

    // ---- M update + read scores (scores -> LDS) ----
    float* Mrow = M + ((size_t)b*1024 + n)*64;
    float dr0=0.f, dr1=0.f, dr2=0.f, dr3=0.f, msq2=0.f;
    #pragma unroll
    for (int w = 0; w < 64; w += 4){
        float4 mv = *(const float4*)(Mrow + w);
        mv.x = mv.x*(1.f - wwv*aux[w+0]) + wwv*aux[64+w+0];
        mv.y = mv.y*(1.f - wwv*aux[w+1]) + wwv*aux[64+w+1];
        mv.z = mv.z*(1.f - wwv*aux[w+2]) + wwv*aux[64+w+2];
        mv.w = mv.w*(1.f - wwv*aux[w+3]) + wwv*aux[64+w+3];
        *(float4*)(Mrow + w) = mv;
        msq2 += mv.x*mv.x + mv.y*mv.y + mv.z*mv.z + mv.w*mv.w;
        dr0 += mv.x*aux[128+(w+0)*4+0] + mv.y*aux[128+(w+1)*4+0] + mv.z*aux[128+(w+2)*4+0] + mv.w*aux[128+(w+3)*4+0];
        dr1 += mv.x*aux[128+(w+0)*4+1] + mv.y*aux[128+(w+1)*4+1] + mv.z*aux[128+(w+2)*4+1] + mv.w*aux[128+(w+3)*4+1];
        dr2 += mv.x*aux[128+(w+0)*4+2] + mv.y*aux[128+(w+1)*4+2] + mv.z*aux[128+(w+2)*4+2] + mv.w*aux[128+(w+3)*4+2];
        dr3 += mv.x*aux[128+(w+0)*4+3] + mv.y*aux[128+(w+1)*4+3] + mv.z*aux[128+(w+2)*4+3] + mv.w*aux[128+(w+3)*4+3];
    }
    float den = sqrtf(msq2) + 1e-8f;
    pS[0*1024 + n] = aux[392]*dr0/den;
    pS[1*1024 + n] = aux[393]*dr1/den;
    pS[2*1024 + n] = aux[394]*dr2/den;
    pS[3*1024 + n] = aux[395]*dr3/den;
    __syncthreads();

    // ---- read softmax per r (r_ = tid>>8 owns 4 n) ----
    const int r_ = tid >> 8, i4 = (tid & 255)*4;
    float v0 = pS[r_*1024 + i4+0], v1 = pS[r_*1024 + i4+1];
    float v2 = pS[r_*1024 + i4+2], v3 = pS[r_*1024 + i4+3];
    float lm = fmaxf(fmaxf(v0,v1), fmaxf(v2,v3));
    #pragma unroll
    for (int off = 32; off > 0; off >>= 1) lm = fmaxf(lm, __shfl_xor(lm, off));
    if (lane == 0) red[wid] = lm;
    __syncthreads();
    if (tid < 4) red[16+tid] = fmaxf(fmaxf(red[4*tid],red[4*tid+1]), fmaxf(red[4*tid+2],red[4*tid+3]));
    __syncthreads();
    float mxr = red[16 + r_];
    float lsum = expf(v0-mxr) + expf(v1-mxr) + expf(v2-mxr) + expf(v3-mxr);
    #pragma unroll
    for (int off = 32; off > 0; off >>= 1) lsum += __shfl_xor(lsum, off);
    if (lane == 0) red[wid] = lsum;
    __syncthreads();
    if (tid < 4) red[20+tid] = red[4*tid]+red[4*tid+1]+red[4*tid+2]+red[4*tid+3];
    __syncthreads();
    float totr = red[20 + r_];
    {
        float w0 = expf(v0-mxr)/totr, w1 = expf(v1-mxr)/totr;
        float w2 = expf(v2-mxr)/totr, w3 = expf(v3-mxr)/totr;
        pS[r_*1024 + i4+0] = w0; pS[r_*1024 + i4+1] = w1;
        pS[r_*1024 + i4+2] = w2; pS[r_*1024 + i4+3] = w3;
        lrw[((size_t)(b*1024 + i4+0))*4 + r_] = w0;
        lrw[((size_t)(b*1024 + i4+1))*4 + r_] = w1;
        lrw[((size_t)(b*1024 + i4+2))*4 + r_] = w2;
        lrw[((size_t)(b*1024 + i4+3))*4 + r_] = w3;
    }
    __syncthreads();

    // ---- read vectors: thread (q = tid>>8, r = (tid>>6)&3, w = tid&63) ----
    {
        const int q = tid >> 8, r = (tid >> 6) & 3, w = tid & 63;
        const float* Mb = M + ((size_t)b*1024 + q*256)*64;
        const float* rb = pS + r*1024 + q*256;
        float acc = 0.f;
        for (int i = 0; i < 256; ++i)
            acc += Mb[(size_t)i*64 + w] * rb[i];
        rvS[tid] = acc;
    }
    __syncthreads();
    if (tid < 256){
        int w2 = tid >> 2, r2 = tid & 3;
        float ssum = 0.f;
        #pragma unroll
        for (int q = 0; q < 4; ++q) ssum += rvS[q*256 + r2*64 + w2];
        lrv[b*256 + tid] = ssum;     // layout [b][w*4+r]
    }
}

// ---------------- final: yt = lrv@Wr + sum(vtp); out = max over t --------------------
// grid (16 m-chunks, 4 b-groups) x 256 thr. thread: 4 m x 1 b.
__global__ void dnc_yfin(const float* __restrict__ lrv, const float* __restrict__ Wr,
                         const float* __restrict__ vtp, float* __restrict__ out, int t){
    const int tid = threadIdx.x;
    const int mg = tid & 31, bgl = tid >> 5;       // bgl 0..7
    const int m0 = blockIdx.x*128 + mg*4;
    const int b  = blockIdx.y*8 + bgl;
    __shared__ float lt[256*9];                    // lrv^T [k][bgl], pad 9
    #pragma unroll
    for (int i = 0; i < 8; ++i)
        lt[tid*9 + i] = lrv[((size_t)(blockIdx.y*8 + i))*256 + tid];
    __syncthreads();
    float4 acc = make_float4(0.f,0.f,0.f,0.f);
    for (int kk = 0; kk < 256; ++kk){
        float av = lt[kk*9 + bgl];
        float4 wv = *(const float4*)&Wr[(size_t)kk*VT + m0];
        acc.x += av*wv.x; acc.y += av*wv.y; acc.z += av*wv.z; acc.w += av*wv.w;
    }
    #pragma unroll
    for (int sp = 0; sp < VKS; ++sp){
        float4 vp = *(const float4*)&vtp[((size_t)sp*BSZ + b)*VT + m0];
        acc.x += vp.x; acc.y += vp.y; acc.z += vp.z; acc.w += vp.w;
    }
    float4* op = (float4*)&out[(size_t)b*VT + m0];
    if (t == 0){ *op = acc; }
    else {
        float4 cur = *op;
        cur.x = fmaxf(cur.x, acc.x); cur.y = fmaxf(cur.y, acc.y);
        cur.z = fmaxf(cur.z, acc.z); cur.w = fmaxf(cur.w, acc.w);
        *op = cur;
    }
}

extern "C" void kernel_launch(void* const* d_in, const int* in_sizes, int n_in,
                              void* d_out, int out_size, void* d_ws, size_t ws_size,
                              hipStream_t stream){
    const float* x      = (const float*)d_in[0];
    const float* mem0   = (const float*)d_in[1];
    const float* Wy     = (const float*)d_in[2];
    const float* WE     = (const float*)d_in[3];
    const float* Wr     = (const float*)d_in[4];
    const float* Wih0   = (const float*)d_in[5];
    const float* Whh0   = (const float*)d_in[6];
    const float* bih0   = (const float*)d_in[7];
    const float* bhh0   = (const float*)d_in[8];
    const float* Wih1   = (const float*)d_in[9];
    const float* Whh1   = (const float*)d_in[10];
    const float* bih1   = (const float*)d_in[11];
    const float* bhh1   = (const float*)d_in[12];
    float* out = (float*)d_out;

    float* p = (float*)d_ws;
    float* M       = p; p += (size_t)BSZ*1024*64;
    float* hstate0 = p; p += 4*BSZ*HD;     // zero block start
    float* hstate1 = p; p += 4*BSZ*HD;
    float* cstate  = p; p += 4*BSZ*HD;
    float* ubuf    = p; p += BSZ*1024;
    float* lww     = p; p += BSZ*1024;
    float* lrw     = p; p += BSZ*1024*4;
    float* lrv     = p; p += BSZ*256;      // zero block end
    float* bnx     = p; p += (size_t)TT*BSZ*XD;
    float* lin1    = p; p += BSZ*1024;
    float* gpart   = p; p += (size_t)2*GKS*BSZ*2048;
    float* flat    = p; p += BSZ*2048;
    float* vtp     = p; p += (size_t)VKS*BSZ*VT;
    float* ep      = p; p += (size_t)VKS*BSZ*ET;
    float* iv      = p; p += BSZ*ET;
    float* allocw  = p; p += BSZ*1024;
    float* scw     = p; p += BSZ*1024;

    (void)hipMemcpyAsync(M, mem0, (size_t)BSZ*1024*64*sizeof(float), hipMemcpyDeviceToDevice, stream);
    size_t zfloats = (size_t)(4*BSZ*HD)*3 + BSZ*1024*2 + BSZ*1024*4 + BSZ*256;
    (void)hipMemsetAsync(hstate0, 0, zfloats*sizeof(float), stream);

    dnc_bnx<<<TT, 128, 0, stream>>>(x, bnx);

    for (int t = 0; t < TT; ++t){
        const float* hr = (t & 1) ? hstate1 : hstate0;
        float*       hw = (t & 1) ? hstate0 : hstate1;
        dnc_lstm_gemm<<<dim3(16,2,GKS), 256, 0, stream>>>(bnx + (size_t)t*BSZ*XD, XD,
            lrv, 256, hr, Wih0, Whh0, gpart);
        dnc_gates<<<128, 256, 0, stream>>>(gpart, bih0, bhh0, cstate, hw, flat, lin1, 0);
        dnc_lstm_gemm<<<dim3(16,2,GKS), 256, 0, stream>>>(lin1, 1024,
            nullptr, 0, hr + 2*BSZ*HD, Wih1, Whh1, gpart);
        dnc_gates<<<128, 256, 0, stream>>>(gpart, bih1, bhh1, cstate, hw, flat, nullptr, 1);
        dnc_gemv2<<<dim3(12,VKS), 256, 0, stream>>>(flat, Wy, WE, vtp, ep);
        dnc_presort_cw<<<64, 1024, 0, stream>>>(ep, lrw, lww, ubuf, iv, allocw, M, scw);
        dnc_memup_rv<<<32, 1024, 0, stream>>>(M, scw, allocw, iv, lww, lrw, lrv);
        dnc_yfin<<<dim3(16,4), 256, 0, stream>>>(lrv, Wr, vtp, out, t);
    }
}

// Round 9
// 4115.779 us; speedup vs baseline: 2.1414x; 2.1414x over previous
//
#include <hip/hip_runtime.h>
#include <math.h>

#define BSZ 32
#define TT  32
#define XD  128
#define HD  512
#define VT  2048
#define ET  463
#define GKS 8
#define VKS 16

__device__ __forceinline__ float sigf(float x){ return 1.f/(1.f+expf(-x)); }
__device__ __forceinline__ float logsigf(float x){
    return (x >= 0.f) ? -log1pf(expf(-x)) : x - log1pf(expf(x));
}

// ---- 1024-thread block reductions (wave shfl + 16 partials; red[17+]) --------------
__device__ __forceinline__ float bsum(float v, float* red, int tid){
    #pragma unroll
    for (int off = 32; off > 0; off >>= 1) v += __shfl_xor(v, off);
    if ((tid & 63) == 0) red[tid >> 6] = v;
    __syncthreads();
    if (tid == 0){
        float s = red[0];
        #pragma unroll
        for (int i = 1; i < 16; ++i) s += red[i];
        red[16] = s;
    }
    __syncthreads();
    float r = red[16];
    __syncthreads();
    return r;
}
__device__ __forceinline__ float bmax(float v, float* red, int tid){
    #pragma unroll
    for (int off = 32; off > 0; off >>= 1) v = fmaxf(v, __shfl_xor(v, off));
    if ((tid & 63) == 0) red[tid >> 6] = v;
    __syncthreads();
    if (tid == 0){
        float s = red[0];
        #pragma unroll
        for (int i = 1; i < 16; ++i) s = fmaxf(s, red[i]);
        red[16] = s;
    }
    __syncthreads();
    float r = red[16];
    __syncthreads();
    return r;
}

// ---------------- batchnorm of x for ALL timesteps (recurrence-independent) ---------
__global__ void dnc_bnx(const float* __restrict__ x, float* __restrict__ bnx){
    int t = blockIdx.x, k = threadIdx.x;   // 128 threads
    float vals[BSZ];
    float s = 0.f;
    #pragma unroll
    for (int b = 0; b < BSZ; ++b){ vals[b] = x[(b*TT + t)*XD + k]; s += vals[b]; }
    float mean = s * (1.f/BSZ);
    float ss = 0.f;
    #pragma unroll
    for (int b = 0; b < BSZ; ++b){ float d = vals[b]-mean; ss += d*d; }
    float inv = 1.f / sqrtf(ss*(1.f/BSZ) + 1e-5f);
    #pragma unroll
    for (int b = 0; b < BSZ; ++b) bnx[((size_t)t*BSZ + b)*XD + k] = (vals[b]-mean)*inv;
}

// ---------------- LSTM pre-activation GEMM, LDS-staged transposed weight tile --------
// grid (16 jchunks, 2 dirs, GKS), block 256. thread: 4 j x 4 b accumulators.
// Weights staged once per block into wtile[kk][j] (1x traffic, conflict-free writes);
// inner loop: 2 ds_read_b128 per kk -> 16 FMA (8 FMA/lane/LDS-instr), no global loads.
__global__ __launch_bounds__(256) void dnc_lstm_gemm(
    const float* __restrict__ srcA, int KA,
    const float* __restrict__ srcB, int KB,
    const float* __restrict__ hbase,
    const float* __restrict__ Wih, const float* __restrict__ Whh,
    float* __restrict__ gpart)
{
    const int jc = blockIdx.x, d = blockIdx.y, ks = blockIdx.z;
    const int tid = threadIdx.x;
    const int jg = tid & 31, bg = tid >> 5;
    const int jbase = jc*128;
    const int j0 = jbase + jg*4;
    const int jg4 = jg*4;
    const int b0 = bg*4;
    const int K1 = KA + KB;
    const int cA = KA >> 6;
    const int cin = K1 >> 6;
    const int nct = cin + 8;               // + HD/64 h-chunks
    const int per = (nct + GKS - 1) / GKS;
    int c0 = ks*per; int c1 = min(nct, c0+per);
    __shared__ __align__(16) float itile[64*36];
    __shared__ __align__(16) float wtile[64*132];
    float acc[4][4] = {{0}};
    for (int c = c0; c < c1; ++c){
        const float* src; int stride, kb, wcol; const float* Wb; int Kw;
        if (c < cA){ src = srcA; stride = KA; kb = c*64; wcol = c*64;
                     Wb = Wih + (size_t)d*2048*K1; Kw = K1; }
        else if (c < cin){ src = srcB; stride = KB; kb = (c-cA)*64; wcol = c*64;
                           Wb = Wih + (size_t)d*2048*K1; Kw = K1; }
        else { src = hbase + d*(BSZ*HD); stride = HD; kb = (c-cin)*64; wcol = kb;
               Wb = Whh + (size_t)d*2048*512; Kw = 512; }
        // input tile [kk][b]
        #pragma unroll
        for (int i = 0; i < 8; ++i){
            int idx = i*256 + tid; int kk = idx & 63, b = idx >> 6;
            itile[kk*36 + b] = src[b*stride + kb + kk];
        }
        // weight tile transposed [kk][j]: consecutive lanes -> consecutive j
        #pragma unroll
        for (int i = 0; i < 8; ++i){
            int fi = i*256 + tid;          // 0..2047
            int j  = fi & 127;             // 0..127
            int kq = fi >> 7;              // 0..15 (k-quad)
            float4 w4 = *(const float4*)&Wb[(size_t)(jbase + j)*Kw + wcol + kq*4];
            wtile[(kq*4+0)*132 + j] = w4.x;
            wtile[(kq*4+1)*132 + j] = w4.y;
            wtile[(kq*4+2)*132 + j] = w4.z;
            wtile[(kq*4+3)*132 + j] = w4.w;
        }
        __syncthreads();
        #pragma unroll 8
        for (int kk = 0; kk < 64; ++kk){
            float4 a = *(const float4*)&itile[kk*36 + b0];
            float4 w = *(const float4*)&wtile[kk*132 + jg4];
            acc[0][0] += w.x*a.x; acc[0][1] += w.x*a.y; acc[0][2] += w.x*a.z; acc[0][3] += w.x*a.w;
            acc[1][0] += w.y*a.x; acc[1][1] += w.y*a.y; acc[1][2] += w.y*a.z; acc[1][3] += w.y*a.w;
            acc[2][0] += w.z*a.x; acc[2][1] += w.z*a.y; acc[2][2] += w.z*a.z; acc[2][3] += w.z*a.w;
            acc[3][0] += w.w*a.x; acc[3][1] += w.w*a.y; acc[3][2] += w.w*a.z; acc[3][3] += w.w*a.w;
        }
        __syncthreads();
    }
    #pragma unroll
    for (int jj = 0; jj < 4; ++jj){
        #pragma unroll
        for (int bb = 0; bb < 4; ++bb)
            gpart[((size_t)(d*GKS + ks)*BSZ + (b0+bb))*2048 + (j0+jj)] = acc[jj][bb];
    }
}

// ---------------- LSTM gates: sum partials -> h, c, flat, optional next input --------
__global__ void dnc_gates(const float* __restrict__ gpart,
                          const float* __restrict__ bih, const float* __restrict__ bhh,
                          float* __restrict__ cstate, float* __restrict__ hwrite,
                          float* __restrict__ flat, float* __restrict__ lout, int l){
    int idx = blockIdx.x*256 + threadIdx.x;
    int u = idx & 511, b = (idx >> 9) & 31, d = idx >> 14;
    int cell = 2*l + d;
    float g[4];
    #pragma unroll
    for (int xg = 0; xg < 4; ++xg){
        int j = xg*512 + u;
        float s = bih[d*2048 + j] + bhh[d*2048 + j];
        #pragma unroll
        for (int ks = 0; ks < GKS; ++ks)
            s += gpart[((size_t)(d*GKS + ks)*BSZ + b)*2048 + j];
        g[xg] = s;
    }
    float ig = sigf(g[0]), fg = sigf(g[1]), og = sigf(g[3]);
    float gg = tanhf(g[2]);
    int ci = (cell*BSZ + b)*HD + u;
    float c2 = fg*cstate[ci] + ig*gg;
    cstate[ci] = c2;
    float h = og*tanhf(c2);
    hwrite[ci] = h;
    flat[b*2048 + cell*HD + u] = h;
    if (lout) lout[b*1024 + d*HD + u] = h;
}

// ---------------- combined GEMV: flat@Wy (bx 0-7, float4 weights) + flat@WE (bx 8-11) -
__global__ void dnc_gemv2(const float* __restrict__ fin, const float* __restrict__ Wy,
                          const float* __restrict__ WE,
                          float* __restrict__ vtp, float* __restrict__ ep){
    const int bx = blockIdx.x, ksi = blockIdx.y;
    const int tid = threadIdx.x;
    const int lane = tid & 63, bg = tid >> 6;
    const int b0 = bg*8;
    const int k0 = ksi*128;
    __shared__ __align__(16) float tile[128*36];
    #pragma unroll
    for (int i = 0; i < 16; ++i){
        int idx = i*256 + tid; int kk = idx & 127, b = idx >> 7;
        tile[kk*36 + b] = fin[b*2048 + k0 + kk];
    }
    __syncthreads();

    if (bx < 8){
        // ---- Wy path: lane owns 4 consecutive m; float4 weight loads ----
        const int m = bx*256 + lane*4;
        float acc[8][4] = {{0}};
        #pragma unroll 4
        for (int kk = 0; kk < 128; ++kk){
            float4 w  = *(const float4*)&Wy[(size_t)(k0+kk)*VT + m];
            float4 a0 = *(const float4*)&tile[kk*36 + b0];
            float4 a1 = *(const float4*)&tile[kk*36 + b0 + 4];
            acc[0][0]+=a0.x*w.x; acc[0][1]+=a0.x*w.y; acc[0][2]+=a0.x*w.z; acc[0][3]+=a0.x*w.w;
            acc[1][0]+=a0.y*w.x; acc[1][1]+=a0.y*w.y; acc[1][2]+=a0.y*w.z; acc[1][3]+=a0.y*w.w;
            acc[2][0]+=a0.z*w.x; acc[2][1]+=a0.z*w.y; acc[2][2]+=a0.z*w.z; acc[2][3]+=a0.z*w.w;
            acc[3][0]+=a0.w*w.x; acc[3][1]+=a0.w*w.y; acc[3][2]+=a0.w*w.z; acc[3][3]+=a0.w*w.w;
            acc[4][0]+=a1.x*w.x; acc[4][1]+=a1.x*w.y; acc[4][2]+=a1.x*w.z; acc[4][3]+=a1.x*w.w;
            acc[5][0]+=a1.y*w.x; acc[5][1]+=a1.y*w.y; acc[5][2]+=a1.y*w.z; acc[5][3]+=a1.y*w.w;
            acc[6][0]+=a1.z*w.x; acc[6][1]+=a1.z*w.y; acc[6][2]+=a1.z*w.z; acc[6][3]+=a1.z*w.w;
            acc[7][0]+=a1.w*w.x; acc[7][1]+=a1.w*w.y; acc[7][2]+=a1.w*w.z; acc[7][3]+=a1.w*w.w;
        }
        #pragma unroll
        for (int bb = 0; bb < 8; ++bb){
            float4 st = make_float4(acc[bb][0], acc[bb][1], acc[bb][2], acc[bb][3]);
            *(float4*)&vtp[((size_t)ksi*BSZ + b0+bb)*VT + m] = st;
        }
    } else {
        // ---- WE path (Mdim 463 odd -> scalar weights, 2 m per thread) ----
        const int mb = bx - 8;
        const int m0 = mb*128 + lane, m1 = m0 + 64;
        bool v0 = m0 < ET, v1 = m1 < ET;
        float acc[16] = {0};
        #pragma unroll 2
        for (int kk = 0; kk < 128; ++kk){
            float4 pq = *(const float4*)&tile[kk*36 + b0];
            float4 qq = *(const float4*)&tile[kk*36 + b0 + 4];
            const float* wr = WE + (size_t)(k0+kk)*ET;
            float w0 = v0 ? wr[m0] : 0.f;
            float w1 = v1 ? wr[m1] : 0.f;
            acc[0]+=pq.x*w0; acc[1]+=pq.y*w0; acc[2]+=pq.z*w0; acc[3]+=pq.w*w0;
            acc[4]+=qq.x*w0; acc[5]+=qq.y*w0; acc[6]+=qq.z*w0; acc[7]+=qq.w*w0;
            acc[8]+=pq.x*w1; acc[9]+=pq.y*w1; acc[10]+=pq.z*w1; acc[11]+=pq.w*w1;
            acc[12]+=qq.x*w1; acc[13]+=qq.y*w1; acc[14]+=qq.z*w1; acc[15]+=qq.w*w1;
        }
        if (v0){
            #pragma unroll
            for (int bb = 0; bb < 8; ++bb)
                ep[((size_t)ksi*BSZ + b0+bb)*ET + m0] = acc[bb];
        }
        if (v1){
            #pragma unroll
            for (int bb = 0; bb < 8; ++bb)
                ep[((size_t)ksi*BSZ + b0+bb)*ET + m1] = acc[8+bb];
        }
    }
}

// ---------------- presort (blocks 0-31) || cw_score (blocks 32-63) -------------------
__global__ __launch_bounds__(1024) void dnc_presort_cw(
    const float* __restrict__ ep, const float* __restrict__ lrw,
    const float* __restrict__ lww, float* __restrict__ ubuf,
    float* __restrict__ iv, float* __restrict__ allocw,
    const float* __restrict__ M, float* __restrict__ scw)
{
    const int bid = blockIdx.x, tid = threadIdx.x;
    const int lane = tid & 63, wid = tid >> 6;
    __shared__ float red[32];
    __shared__ float ivS[464];
    __shared__ unsigned long long keysS[1024];
    __shared__ float wtot[16], wpref[16];

    if (bid < 32){
        const int b = bid;
        // layernorm of WE partial sums -> iv
        float myv = 0.f;
        if (tid < ET){
            #pragma unroll
            for (int s = 0; s < VKS; ++s) myv += ep[((size_t)s*BSZ + b)*ET + tid];
        }
        float mean = bsum(myv, red, tid) * (1.f/ET);
        float dd = (tid < ET) ? (myv - mean) : 0.f;
        float var = bsum(dd*dd, red, tid) * (1.f/ET);
        float rinv = 1.f / sqrtf(var + 1e-5f);
        float ivv = (myv - mean)*rinv;
        if (tid < ET){ ivS[tid] = ivv; iv[b*ET + tid] = ivv; }
        __syncthreads();

        // usage
        const int n = tid;
        float4 lw4 = *(const float4*)&lrw[((size_t)b*1024 + n)*4];
        float f0 = sigf(ivS[453]), f1 = sigf(ivS[454]), f2 = sigf(ivS[455]), f3 = sigf(ivS[456]);
        float ret = (1.f-f0*lw4.x)*(1.f-f1*lw4.y)*(1.f-f2*lw4.z)*(1.f-f3*lw4.w);
        float uo = ubuf[b*1024+n], lwo = lww[b*1024+n];
        float un = (uo + lwo - uo*lwo)*ret;
        ubuf[b*1024+n] = un;

        // hybrid bitonic sort (LDS j>=64, shfl j<64); u>=0 so uint order == float order
        unsigned long long key = ((unsigned long long)__float_as_uint(un) << 32) | (unsigned)tid;
        for (int k = 2; k <= 1024; k <<= 1){
            int j = k >> 1;
            for (; j >= 64; j >>= 1){
                keysS[tid] = key; __syncthreads();
                unsigned long long other = keysS[tid ^ j];
                bool up = ((tid & k) == 0);
                bool takeMin = (((tid & j) == 0) == up);
                key = takeMin ? (key < other ? key : other) : (key > other ? key : other);
                __syncthreads();
            }
            for (; j >= 1; j >>= 1){
                unsigned long long other = __shfl_xor(key, j);
                bool up = ((tid & k) == 0);
                bool takeMin = (((tid & j) == 0) == up);
                key = takeMin ? (key < other ? key : other) : (key > other ? key : other);
            }
        }
        float su = __uint_as_float((unsigned)(key >> 32));
        int idxv = (int)(key & 0xffffffffu);

        // exclusive cumprod via wave shfl scan + 16 wave totals
        float p = su;
        #pragma unroll
        for (int o = 1; o < 64; o <<= 1){ float q = __shfl_up(p, o); if (lane >= o) p *= q; }
        if (lane == 63) wtot[wid] = p;
        __syncthreads();
        if (tid == 0){
            float r = 1.f;
            #pragma unroll
            for (int i = 0; i < 16; ++i){ wpref[i] = r; r *= wtot[i]; }
        }
        __syncthreads();
        float excl = __shfl_up(p, 1); if (lane == 0) excl = 1.f;
        float cpx = excl * wpref[wid];
        allocw[b*1024 + idxv] = (1.f - su)*cpx;
    } else {
        const int b = bid - 32;
        // mini-layernorm recompute (cheap; breaks same-stage dependency on iv)
        float myv = 0.f;
        if (tid < ET){
            #pragma unroll
            for (int s = 0; s < VKS; ++s) myv += ep[((size_t)s*BSZ + b)*ET + tid];
        }
        float mean = bsum(myv, red, tid) * (1.f/ET);
        float dd = (tid < ET) ? (myv - mean) : 0.f;
        float var = bsum(dd*dd, red, tid) * (1.f/ET);
        float rinv = 1.f / sqrtf(var + 1e-5f);
        float ivv = (myv - mean)*rinv;
        if (tid >= 260 && tid < 324) ivS[tid - 260] = ivv;   // write key
        if (tid == 324) ivS[64] = 1.f - logsigf(ivv);        // wbeta
        __syncthreads();
        float ksq = 0.f;
        #pragma unroll
        for (int w = 0; w < 64; ++w) ksq += ivS[w]*ivS[w];
        float kden = sqrtf(ksq) + 1e-8f;
        float wb = ivS[64];
        const float* Mrow = M + ((size_t)b*1024 + tid)*64;
        float dot = 0.f, msq = 0.f;
        #pragma unroll
        for (int w = 0; w < 64; w += 4){
            float4 mv = *(const float4*)(Mrow + w);
            dot += mv.x*ivS[w] + mv.y*ivS[w+1] + mv.z*ivS[w+2] + mv.w*ivS[w+3];
            msq += mv.x*mv.x + mv.y*mv.y + mv.z*mv.z + mv.w*mv.w;
        }
        scw[b*1024 + tid] = wb*dot/((sqrtf(msq) + 1e-8f)*kden);
    }
}

// ------- fused memory tail (32 blks x 1024): cw-softmax+ww, M update, read scores,
//         read softmax, read vectors. scr lives in LDS; M re-read via same-CU L1/L2. --
__global__ __launch_bounds__(1024) void dnc_memup_rv(
    float* __restrict__ M, const float* __restrict__ scw,
    const float* __restrict__ allocw, const float* __restrict__ iv,
    float* __restrict__ lww, float* __restrict__ lrw, float* __restrict__ lrv)
{
    const int b = blockIdx.x, tid = threadIdx.x;
    const int lane = tid & 63, wid = tid >> 6;
    __shared__ float red[32];
    __shared__ float aux[400];
    __shared__ float pS[4096];     // [r][n] scores then rw
    __shared__ float rvS[1024];
    const int n = tid;

    // ---- content-write softmax + ww ----
    float s = scw[b*1024 + n];
    float mx = bmax(s, red, tid);
    float tot = bsum(expf(s - mx), red, tid);
    float cwv = expf(s - mx)/tot;
    float ag = sigf(iv[b*ET + 457]), wg = sigf(iv[b*ET + 458]);
    float wwv = wg*(ag*allocw[b*1024 + n] + (1.f-ag)*cwv);
    lww[b*1024 + n] = wwv;

    // stage erase[0..63], wvec[64..127], rkn[128..383], nrm[384..387], rb[392..395]
    if (tid < 64){ aux[tid] = sigf(iv[b*ET + 325 + tid]); aux[64+tid] = iv[b*ET + 389 + tid]; }
    if (tid >= 64 && tid < 320) aux[64 + tid] = iv[b*ET + (tid - 64)];
    if (tid >= 320 && tid < 324) aux[72 + tid] = 1.f - logsigf(iv[b*ET + 256 + (tid - 320)]);
    __syncthreads();
    if (tid < 4){
        float ss = 0.f;
        #pragma unroll
        for (int w = 0; w < 64; ++w){ float v = aux[128 + w*4 + tid]; ss += v*v; }
        aux[384 + tid] = sqrtf(ss) + 1e-8f;
    }
    __syncthreads();
    if (tid < 256) aux[128 + tid] = aux[128 + tid] / aux[384 + (tid & 3)];
    __syncthreads();

    // ---- M update + read scores (scores -> LDS) ----
    float* Mrow = M + ((size_t)b*1024 + n)*64;
    float dr0=0.f, dr1=0.f, dr2=0.f, dr3=0.f, msq2=0.f;
    #pragma unroll
    for (int w = 0; w < 64; w += 4){
        float4 mv = *(const float4*)(Mrow + w);
        mv.x = mv.x*(1.f - wwv*aux[w+0]) + wwv*aux[64+w+0];
        mv.y = mv.y*(1.f - wwv*aux[w+1]) + wwv*aux[64+w+1];
        mv.z = mv.z*(1.f - wwv*aux[w+2]) + wwv*aux[64+w+2];
        mv.w = mv.w*(1.f - wwv*aux[w+3]) + wwv*aux[64+w+3];
        *(float4*)(Mrow + w) = mv;
        msq2 += mv.x*mv.x + mv.y*mv.y + mv.z*mv.z + mv.w*mv.w;
        dr0 += mv.x*aux[128+(w+0)*4+0] + mv.y*aux[128+(w+1)*4+0] + mv.z*aux[128+(w+2)*4+0] + mv.w*aux[128+(w+3)*4+0];
        dr1 += mv.x*aux[128+(w+0)*4+1] + mv.y*aux[128+(w+1)*4+1] + mv.z*aux[128+(w+2)*4+1] + mv.w*aux[128+(w+3)*4+1];
        dr2 += mv.x*aux[128+(w+0)*4+2] + mv.y*aux[128+(w+1)*4+2] + mv.z*aux[128+(w+2)*4+2] + mv.w*aux[128+(w+3)*4+2];
        dr3 += mv.x*aux[128+(w+0)*4+3] + mv.y*aux[128+(w+1)*4+3] + mv.z*aux[128+(w+2)*4+3] + mv.w*aux[128+(w+3)*4+3];
    }
    float den = sqrtf(msq2) + 1e-8f;
    pS[0*1024 + n] = aux[392]*dr0/den;
    pS[1*1024 + n] = aux[393]*dr1/den;
    pS[2*1024 + n] = aux[394]*dr2/den;
    pS[3*1024 + n] = aux[395]*dr3/den;
    __syncthreads();

    // ---- read softmax per r (r_ = tid>>8 owns 4 n) ----
    const int r_ = tid >> 8, i4 = (tid & 255)*4;
    float v0 = pS[r_*1024 + i4+0], v1 = pS[r_*1024 + i4+1];
    float v2 = pS[r_*1024 + i4+2], v3 = pS[r_*1024 + i4+3];
    float lm = fmaxf(fmaxf(v0,v1), fmaxf(v2,v3));
    #pragma unroll
    for (int off = 32; off > 0; off >>= 1) lm = fmaxf(lm, __shfl_xor(lm, off));
    if (lane == 0) red[wid] = lm;
    __syncthreads();
    if (tid < 4) red[16+tid] = fmaxf(fmaxf(red[4*tid],red[4*tid+1]), fmaxf(red[4*tid+2],red[4*tid+3]));
    __syncthreads();
    float mxr = red[16 + r_];
    float lsum = expf(v0-mxr) + expf(v1-mxr) + expf(v2-mxr) + expf(v3-mxr);
    #pragma unroll
    for (int off = 32; off > 0; off >>= 1) lsum += __shfl_xor(lsum, off);
    if (lane == 0) red[wid] = lsum;
    __syncthreads();
    if (tid < 4) red[20+tid] = red[4*tid]+red[4*tid+1]+red[4*tid+2]+red[4*tid+3];
    __syncthreads();
    float totr = red[20 + r_];
    {
        float w0 = expf(v0-mxr)/totr, w1 = expf(v1-mxr)/totr;
        float w2 = expf(v2-mxr)/totr, w3 = expf(v3-mxr)/totr;
        pS[r_*1024 + i4+0] = w0; pS[r_*1024 + i4+1] = w1;
        pS[r_*1024 + i4+2] = w2; pS[r_*1024 + i4+3] = w3;
        lrw[((size_t)(b*1024 + i4+0))*4 + r_] = w0;
        lrw[((size_t)(b*1024 + i4+1))*4 + r_] = w1;
        lrw[((size_t)(b*1024 + i4+2))*4 + r_] = w2;
        lrw[((size_t)(b*1024 + i4+3))*4 + r_] = w3;
    }
    __syncthreads();

    // ---- read vectors: thread (q = tid>>8, r = (tid>>6)&3, w = tid&63) ----
    {
        const int q = tid >> 8, r = (tid >> 6) & 3, w = tid & 63;
        const float* Mb = M + ((size_t)b*1024 + q*256)*64;
        const float* rb = pS + r*1024 + q*256;
        float acc = 0.f;
        for (int i = 0; i < 256; ++i)
            acc += Mb[(size_t)i*64 + w] * rb[i];
        rvS[tid] = acc;
    }
    __syncthreads();
    if (tid < 256){
        int w2 = tid >> 2, r2 = tid & 3;
        float ssum = 0.f;
        #pragma unroll
        for (int q = 0; q < 4; ++q) ssum += rvS[q*256 + r2*64 + w2];
        lrv[b*256 + tid] = ssum;     // layout [b][w*4+r]
    }
}

// ---------------- final: yt = lrv@Wr + sum(vtp); out = max over t --------------------
// grid (16 m-chunks, 4 b-groups) x 256 thr. thread: 4 m x 1 b.
__global__ void dnc_yfin(const float* __restrict__ lrv, const float* __restrict__ Wr,
                         const float* __restrict__ vtp, float* __restrict__ out, int t){
    const int tid = threadIdx.x;
    const int mg = tid & 31, bgl = tid >> 5;       // bgl 0..7
    const int m0 = blockIdx.x*128 + mg*4;
    const int b  = blockIdx.y*8 + bgl;
    __shared__ float lt[256*9];                    // lrv^T [k][bgl], pad 9
    #pragma unroll
    for (int i = 0; i < 8; ++i)
        lt[tid*9 + i] = lrv[((size_t)(blockIdx.y*8 + i))*256 + tid];
    __syncthreads();
    float4 acc = make_float4(0.f,0.f,0.f,0.f);
    for (int kk = 0; kk < 256; ++kk){
        float av = lt[kk*9 + bgl];
        float4 wv = *(const float4*)&Wr[(size_t)kk*VT + m0];
        acc.x += av*wv.x; acc.y += av*wv.y; acc.z += av*wv.z; acc.w += av*wv.w;
    }
    #pragma unroll
    for (int sp = 0; sp < VKS; ++sp){
        float4 vp = *(const float4*)&vtp[((size_t)sp*BSZ + b)*VT + m0];
        acc.x += vp.x; acc.y += vp.y; acc.z += vp.z; acc.w += vp.w;
    }
    float4* op = (float4*)&out[(size_t)b*VT + m0];
    if (t == 0){ *op = acc; }
    else {
        float4 cur = *op;
        cur.x = fmaxf(cur.x, acc.x); cur.y = fmaxf(cur.y, acc.y);
        cur.z = fmaxf(cur.z, acc.z); cur.w = fmaxf(cur.w, acc.w);
        *op = cur;
    }
}

extern "C" void kernel_launch(void* const* d_in, const int* in_sizes, int n_in,
                              void* d_out, int out_size, void* d_ws, size_t ws_size,
                              hipStream_t stream){
    const float* x      = (const float*)d_in[0];
    const float* mem0   = (const float*)d_in[1];
    const float* Wy     = (const float*)d_in[2];
    const float* WE     = (const float*)d_in[3];
    const float* Wr     = (const float*)d_in[4];
    const float* Wih0   = (const float*)d_in[5];
    const float* Whh0   = (const float*)d_in[6];
    const float* bih0   = (const float*)d_in[7];
    const float* bhh0   = (const float*)d_in[8];
    const float* Wih1   = (const float*)d_in[9];
    const float* Whh1   = (const float*)d_in[10];
    const float* bih1   = (const float*)d_in[11];
    const float* bhh1   = (const float*)d_in[12];
    float* out = (float*)d_out;

    float* p = (float*)d_ws;
    float* M       = p; p += (size_t)BSZ*1024*64;
    float* hstate0 = p; p += 4*BSZ*HD;     // zero block start
    float* hstate1 = p; p += 4*BSZ*HD;
    float* cstate  = p; p += 4*BSZ*HD;
    float* ubuf    = p; p += BSZ*1024;
    float* lww     = p; p += BSZ*1024;
    float* lrw     = p; p += BSZ*1024*4;
    float* lrv     = p; p += BSZ*256;      // zero block end
    float* bnx     = p; p += (size_t)TT*BSZ*XD;
    float* lin1    = p; p += BSZ*1024;
    float* gpart   = p; p += (size_t)2*GKS*BSZ*2048;
    float* flat    = p; p += BSZ*2048;
    float* vtp     = p; p += (size_t)VKS*BSZ*VT;
    float* ep      = p; p += (size_t)VKS*BSZ*ET;
    float* iv      = p; p += BSZ*ET;
    float* allocw  = p; p += BSZ*1024;
    float* scw     = p; p += BSZ*1024;

    (void)hipMemcpyAsync(M, mem0, (size_t)BSZ*1024*64*sizeof(float), hipMemcpyDeviceToDevice, stream);
    size_t zfloats = (size_t)(4*BSZ*HD)*3 + BSZ*1024*2 + BSZ*1024*4 + BSZ*256;
    (void)hipMemsetAsync(hstate0, 0, zfloats*sizeof(float), stream);

    dnc_bnx<<<TT, 128, 0, stream>>>(x, bnx);

    for (int t = 0; t < TT; ++t){
        const float* hr = (t & 1) ? hstate1 : hstate0;
        float*       hw = (t & 1) ? hstate0 : hstate1;
        dnc_lstm_gemm<<<dim3(16,2,GKS), 256, 0, stream>>>(bnx + (size_t)t*BSZ*XD, XD,
            lrv, 256, hr, Wih0, Whh0, gpart);
        dnc_gates<<<128, 256, 0, stream>>>(gpart, bih0, bhh0, cstate, hw, flat, lin1, 0);
        dnc_lstm_gemm<<<dim3(16,2,GKS), 256, 0, stream>>>(lin1, 1024,
            nullptr, 0, hr + 2*BSZ*HD, Wih1, Whh1, gpart);
        dnc_gates<<<128, 256, 0, stream>>>(gpart, bih1, bhh1, cstate, hw, flat, nullptr, 1);
        dnc_gemv2<<<dim3(12,VKS), 256, 0, stream>>>(flat, Wy, WE, vtp, ep);
        dnc_presort_cw<<<64, 1024, 0, stream>>>(ep, lrw, lww, ubuf, iv, allocw, M, scw);
        dnc_memup_rv<<<32, 1024, 0, stream>>>(M, scw, allocw, iv, lww, lrw, lrv);
        dnc_yfin<<<dim3(16,4), 256, 0, stream>>>(lrv, Wr, vtp, out, t);
    }
}

// Round 10
// 3919.363 us; speedup vs baseline: 2.2487x; 1.0501x over previous
//
#include <hip/hip_runtime.h>
#include <math.h>

#define BSZ 32
#define TT  32
#define XD  128
#define HD  512
#define VT  2048
#define ET  463
#define GKS 8
#define VKS 16

__device__ __forceinline__ float sigf(float x){ return 1.f/(1.f+expf(-x)); }
__device__ __forceinline__ float logsigf(float x){
    return (x >= 0.f) ? -log1pf(expf(-x)) : x - log1pf(expf(x));
}

// ---- 1024-thread block reductions (wave shfl + 16 partials; red[17+]) --------------
__device__ __forceinline__ float bsum(float v, float* red, int tid){
    #pragma unroll
    for (int off = 32; off > 0; off >>= 1) v += __shfl_xor(v, off);
    if ((tid & 63) == 0) red[tid >> 6] = v;
    __syncthreads();
    if (tid == 0){
        float s = red[0];
        #pragma unroll
        for (int i = 1; i < 16; ++i) s += red[i];
        red[16] = s;
    }
    __syncthreads();
    float r = red[16];
    __syncthreads();
    return r;
}
__device__ __forceinline__ float bmax(float v, float* red, int tid){
    #pragma unroll
    for (int off = 32; off > 0; off >>= 1) v = fmaxf(v, __shfl_xor(v, off));
    if ((tid & 63) == 0) red[tid >> 6] = v;
    __syncthreads();
    if (tid == 0){
        float s = red[0];
        #pragma unroll
        for (int i = 1; i < 16; ++i) s = fmaxf(s, red[i]);
        red[16] = s;
    }
    __syncthreads();
    float r = red[16];
    __syncthreads();
    return r;
}

// ---------------- batchnorm of x for ALL timesteps (recurrence-independent) ---------
__global__ void dnc_bnx(const float* __restrict__ x, float* __restrict__ bnx){
    int t = blockIdx.x, k = threadIdx.x;   // 128 threads
    float vals[BSZ];
    float s = 0.f;
    #pragma unroll
    for (int b = 0; b < BSZ; ++b){ vals[b] = x[(b*TT + t)*XD + k]; s += vals[b]; }
    float mean = s * (1.f/BSZ);
    float ss = 0.f;
    #pragma unroll
    for (int b = 0; b < BSZ; ++b){ float d = vals[b]-mean; ss += d*d; }
    float inv = 1.f / sqrtf(ss*(1.f/BSZ) + 1e-5f);
    #pragma unroll
    for (int b = 0; b < BSZ; ++b) bnx[((size_t)t*BSZ + b)*XD + k] = (vals[b]-mean)*inv;
}

// ---------------- shared GEMM body: LDS-staged transposed weight tile ----------------
__device__ __forceinline__ void lstm_gemm_body(
    const float* __restrict__ srcA, int KA,
    const float* __restrict__ srcB, int KB,
    const float* __restrict__ hbase,
    const float* __restrict__ Wih, const float* __restrict__ Whh,
    float* __restrict__ gpart, int jc, int d, int ks, int tid,
    float* itile, float* wtile)
{
    const int jg = tid & 31, bg = tid >> 5;
    const int jbase = jc*128;
    const int j0 = jbase + jg*4;
    const int jg4 = jg*4;
    const int b0 = bg*4;
    const int K1 = KA + KB;
    const int cA = KA >> 6;
    const int cin = K1 >> 6;
    const int nct = cin + 8;               // + HD/64 h-chunks
    const int per = (nct + GKS - 1) / GKS;
    int c0 = ks*per; int c1 = min(nct, c0+per);
    float acc[4][4] = {{0}};
    for (int c = c0; c < c1; ++c){
        const float* src; int stride, kb, wcol; const float* Wb; int Kw;
        if (c < cA){ src = srcA; stride = KA; kb = c*64; wcol = c*64;
                     Wb = Wih + (size_t)d*2048*K1; Kw = K1; }
        else if (c < cin){ src = srcB; stride = KB; kb = (c-cA)*64; wcol = c*64;
                           Wb = Wih + (size_t)d*2048*K1; Kw = K1; }
        else { src = hbase + d*(BSZ*HD); stride = HD; kb = (c-cin)*64; wcol = kb;
               Wb = Whh + (size_t)d*2048*512; Kw = 512; }
        // input tile [kk][b]
        #pragma unroll
        for (int i = 0; i < 8; ++i){
            int idx = i*256 + tid; int kk = idx & 63, b = idx >> 6;
            itile[kk*36 + b] = src[b*stride + kb + kk];
        }
        // weight tile transposed [kk][j]: consecutive lanes -> consecutive j
        #pragma unroll
        for (int i = 0; i < 8; ++i){
            int fi = i*256 + tid;          // 0..2047
            int j  = fi & 127;             // 0..127
            int kq = fi >> 7;              // 0..15 (k-quad)
            float4 w4 = *(const float4*)&Wb[(size_t)(jbase + j)*Kw + wcol + kq*4];
            wtile[(kq*4+0)*132 + j] = w4.x;
            wtile[(kq*4+1)*132 + j] = w4.y;
            wtile[(kq*4+2)*132 + j] = w4.z;
            wtile[(kq*4+3)*132 + j] = w4.w;
        }
        __syncthreads();
        #pragma unroll 8
        for (int kk = 0; kk < 64; ++kk){
            float4 a = *(const float4*)&itile[kk*36 + b0];
            float4 w = *(const float4*)&wtile[kk*132 + jg4];
            acc[0][0] += w.x*a.x; acc[0][1] += w.x*a.y; acc[0][2] += w.x*a.z; acc[0][3] += w.x*a.w;
            acc[1][0] += w.y*a.x; acc[1][1] += w.y*a.y; acc[1][2] += w.y*a.z; acc[1][3] += w.y*a.w;
            acc[2][0] += w.z*a.x; acc[2][1] += w.z*a.y; acc[2][2] += w.z*a.z; acc[2][3] += w.z*a.w;
            acc[3][0] += w.w*a.x; acc[3][1] += w.w*a.y; acc[3][2] += w.w*a.z; acc[3][3] += w.w*a.w;
        }
        __syncthreads();
    }
    #pragma unroll
    for (int jj = 0; jj < 4; ++jj){
        #pragma unroll
        for (int bb = 0; bb < 4; ++bb)
            gpart[((size_t)(d*GKS + ks)*BSZ + (b0+bb))*2048 + (j0+jj)] = acc[jj][bb];
    }
}

// ---------------- shared yfin body ---------------------------------------------------
__device__ __forceinline__ void yfin_body(
    const float* __restrict__ lrv, const float* __restrict__ Wr,
    const float* __restrict__ vtp, float* __restrict__ out, int t,
    int mi, int bgi, int tid, float* lt)
{
    const int mg = tid & 31, bgl = tid >> 5;       // bgl 0..7
    const int m0 = mi*128 + mg*4;
    const int b  = bgi*8 + bgl;
    #pragma unroll
    for (int i = 0; i < 8; ++i)
        lt[tid*9 + i] = lrv[((size_t)(bgi*8 + i))*256 + tid];
    __syncthreads();
    float4 acc = make_float4(0.f,0.f,0.f,0.f);
    for (int kk = 0; kk < 256; ++kk){
        float av = lt[kk*9 + bgl];
        float4 wv = *(const float4*)&Wr[(size_t)kk*VT + m0];
        acc.x += av*wv.x; acc.y += av*wv.y; acc.z += av*wv.z; acc.w += av*wv.w;
    }
    #pragma unroll
    for (int sp = 0; sp < VKS; ++sp){
        float4 vp = *(const float4*)&vtp[((size_t)sp*BSZ + b)*VT + m0];
        acc.x += vp.x; acc.y += vp.y; acc.z += vp.z; acc.w += vp.w;
    }
    float4* op = (float4*)&out[(size_t)b*VT + m0];
    if (t == 0){ *op = acc; }
    else {
        float4 cur = *op;
        cur.x = fmaxf(cur.x, acc.x); cur.y = fmaxf(cur.y, acc.y);
        cur.z = fmaxf(cur.z, acc.z); cur.w = fmaxf(cur.w, acc.w);
        *op = cur;
    }
}

// ---------------- layer-0 GEMM (blocks 0-255) + yfin of PREVIOUS t (blocks 256-319) --
__global__ __launch_bounds__(256) void dnc_gemm0_yfin(
    const float* __restrict__ srcA,
    const float* __restrict__ lrv, const float* __restrict__ hbase,
    const float* __restrict__ Wih, const float* __restrict__ Whh,
    float* __restrict__ gpart,
    const float* __restrict__ Wr, const float* __restrict__ vtp,
    float* __restrict__ out, int tprev)
{
    __shared__ __align__(16) float itile[64*36];
    __shared__ __align__(16) float wtile[64*132];
    const int bid = blockIdx.x, tid = threadIdx.x;
    if (bid < 256){
        lstm_gemm_body(srcA, XD, lrv, 256, hbase, Wih, Whh, gpart,
                       bid & 15, (bid >> 4) & 1, bid >> 5, tid, itile, wtile);
    } else {
        if (tprev < 0) return;
        int yb = bid - 256;                 // 0..63
        yfin_body(lrv, Wr, vtp, out, tprev, yb & 15, yb >> 4, tid, itile);
    }
}

// ---------------- standalone layer-1 GEMM --------------------------------------------
__global__ __launch_bounds__(256) void dnc_lstm_gemm(
    const float* __restrict__ srcA, int KA,
    const float* __restrict__ srcB, int KB,
    const float* __restrict__ hbase,
    const float* __restrict__ Wih, const float* __restrict__ Whh,
    float* __restrict__ gpart)
{
    __shared__ __align__(16) float itile[64*36];
    __shared__ __align__(16) float wtile[64*132];
    lstm_gemm_body(srcA, KA, srcB, KB, hbase, Wih, Whh, gpart,
                   blockIdx.x, blockIdx.y, blockIdx.z, threadIdx.x, itile, wtile);
}

// ---------------- standalone yfin (final timestep) -----------------------------------
__global__ void dnc_yfin(const float* __restrict__ lrv, const float* __restrict__ Wr,
                         const float* __restrict__ vtp, float* __restrict__ out, int t){
    __shared__ float lt[256*9];
    yfin_body(lrv, Wr, vtp, out, t, blockIdx.x, blockIdx.y, threadIdx.x, lt);
}

// ---------------- LSTM gates: sum partials -> h, c, flat, optional next input --------
__global__ void dnc_gates(const float* __restrict__ gpart,
                          const float* __restrict__ bih, const float* __restrict__ bhh,
                          float* __restrict__ cstate, float* __restrict__ hwrite,
                          float* __restrict__ flat, float* __restrict__ lout, int l){
    int idx = blockIdx.x*256 + threadIdx.x;
    int u = idx & 511, b = (idx >> 9) & 31, d = idx >> 14;
    int cell = 2*l + d;
    float g[4];
    #pragma unroll
    for (int xg = 0; xg < 4; ++xg){
        int j = xg*512 + u;
        float s = bih[d*2048 + j] + bhh[d*2048 + j];
        #pragma unroll
        for (int ks = 0; ks < GKS; ++ks)
            s += gpart[((size_t)(d*GKS + ks)*BSZ + b)*2048 + j];
        g[xg] = s;
    }
    float ig = sigf(g[0]), fg = sigf(g[1]), og = sigf(g[3]);
    float gg = tanhf(g[2]);
    int ci = (cell*BSZ + b)*HD + u;
    float c2 = fg*cstate[ci] + ig*gg;
    cstate[ci] = c2;
    float h = og*tanhf(c2);
    hwrite[ci] = h;
    flat[b*2048 + cell*HD + u] = h;
    if (lout) lout[b*1024 + d*HD + u] = h;
}

// ---------------- combined GEMV: flat@Wy (bx 0-7, float4 weights) + flat@WE (bx 8-11) -
__global__ void dnc_gemv2(const float* __restrict__ fin, const float* __restrict__ Wy,
                          const float* __restrict__ WE,
                          float* __restrict__ vtp, float* __restrict__ ep){
    const int bx = blockIdx.x, ksi = blockIdx.y;
    const int tid = threadIdx.x;
    const int lane = tid & 63, bg = tid >> 6;
    const int b0 = bg*8;
    const int k0 = ksi*128;
    __shared__ __align__(16) float tile[128*36];
    #pragma unroll
    for (int i = 0; i < 16; ++i){
        int idx = i*256 + tid; int kk = idx & 127, b = idx >> 7;
        tile[kk*36 + b] = fin[b*2048 + k0 + kk];
    }
    __syncthreads();

    if (bx < 8){
        const int m = bx*256 + lane*4;
        float acc[8][4] = {{0}};
        #pragma unroll 4
        for (int kk = 0; kk < 128; ++kk){
            float4 w  = *(const float4*)&Wy[(size_t)(k0+kk)*VT + m];
            float4 a0 = *(const float4*)&tile[kk*36 + b0];
            float4 a1 = *(const float4*)&tile[kk*36 + b0 + 4];
            acc[0][0]+=a0.x*w.x; acc[0][1]+=a0.x*w.y; acc[0][2]+=a0.x*w.z; acc[0][3]+=a0.x*w.w;
            acc[1][0]+=a0.y*w.x; acc[1][1]+=a0.y*w.y; acc[1][2]+=a0.y*w.z; acc[1][3]+=a0.y*w.w;
            acc[2][0]+=a0.z*w.x; acc[2][1]+=a0.z*w.y; acc[2][2]+=a0.z*w.z; acc[2][3]+=a0.z*w.w;
            acc[3][0]+=a0.w*w.x; acc[3][1]+=a0.w*w.y; acc[3][2]+=a0.w*w.z; acc[3][3]+=a0.w*w.w;
            acc[4][0]+=a1.x*w.x; acc[4][1]+=a1.x*w.y; acc[4][2]+=a1.x*w.z; acc[4][3]+=a1.x*w.w;
            acc[5][0]+=a1.y*w.x; acc[5][1]+=a1.y*w.y; acc[5][2]+=a1.y*w.z; acc[5][3]+=a1.y*w.w;
            acc[6][0]+=a1.z*w.x; acc[6][1]+=a1.z*w.y; acc[6][2]+=a1.z*w.z; acc[6][3]+=a1.z*w.w;
            acc[7][0]+=a1.w*w.x; acc[7][1]+=a1.w*w.y; acc[7][2]+=a1.w*w.z; acc[7][3]+=a1.w*w.w;
        }
        #pragma unroll
        for (int bb = 0; bb < 8; ++bb){
            float4 st = make_float4(acc[bb][0], acc[bb][1], acc[bb][2], acc[bb][3]);
            *(float4*)&vtp[((size_t)ksi*BSZ + b0+bb)*VT + m] = st;
        }
    } else {
        const int mb = bx - 8;
        const int m0 = mb*128 + lane, m1 = m0 + 64;
        bool v0 = m0 < ET, v1 = m1 < ET;
        float acc[16] = {0};
        #pragma unroll 2
        for (int kk = 0; kk < 128; ++kk){
            float4 pq = *(const float4*)&tile[kk*36 + b0];
            float4 qq = *(const float4*)&tile[kk*36 + b0 + 4];
            const float* wr = WE + (size_t)(k0+kk)*ET;
            float w0 = v0 ? wr[m0] : 0.f;
            float w1 = v1 ? wr[m1] : 0.f;
            acc[0]+=pq.x*w0; acc[1]+=pq.y*w0; acc[2]+=pq.z*w0; acc[3]+=pq.w*w0;
            acc[4]+=qq.x*w0; acc[5]+=qq.y*w0; acc[6]+=qq.z*w0; acc[7]+=qq.w*w0;
            acc[8]+=pq.x*w1; acc[9]+=pq.y*w1; acc[10]+=pq.z*w1; acc[11]+=pq.w*w1;
            acc[12]+=qq.x*w1; acc[13]+=qq.y*w1; acc[14]+=qq.z*w1; acc[15]+=qq.w*w1;
        }
        if (v0){
            #pragma unroll
            for (int bb = 0; bb < 8; ++bb)
                ep[((size_t)ksi*BSZ + b0+bb)*ET + m0] = acc[bb];
        }
        if (v1){
            #pragma unroll
            for (int bb = 0; bb < 8; ++bb)
                ep[((size_t)ksi*BSZ + b0+bb)*ET + m1] = acc[8+bb];
        }
    }
}

// ---------------- presort (blocks 0-31) || cw_score (blocks 32-63) -------------------
__global__ __launch_bounds__(1024) void dnc_presort_cw(
    const float* __restrict__ ep, const float* __restrict__ lrw,
    const float* __restrict__ lww, float* __restrict__ ubuf,
    float* __restrict__ iv, float* __restrict__ allocw,
    const float* __restrict__ M, float* __restrict__ scw)
{
    const int bid = blockIdx.x, tid = threadIdx.x;
    const int lane = tid & 63, wid = tid >> 6;
    __shared__ float red[32];
    __shared__ float ivS[464];
    __shared__ unsigned long long keysS[1024];
    __shared__ float wtot[16], wpref[16];

    if (bid < 32){
        const int b = bid;
        float myv = 0.f;
        if (tid < ET){
            #pragma unroll
            for (int s = 0; s < VKS; ++s) myv += ep[((size_t)s*BSZ + b)*ET + tid];
        }
        float mean = bsum(myv, red, tid) * (1.f/ET);
        float dd = (tid < ET) ? (myv - mean) : 0.f;
        float var = bsum(dd*dd, red, tid) * (1.f/ET);
        float rinv = 1.f / sqrtf(var + 1e-5f);
        float ivv = (myv - mean)*rinv;
        if (tid < ET){ ivS[tid] = ivv; iv[b*ET + tid] = ivv; }
        __syncthreads();

        const int n = tid;
        float4 lw4 = *(const float4*)&lrw[((size_t)b*1024 + n)*4];
        float f0 = sigf(ivS[453]), f1 = sigf(ivS[454]), f2 = sigf(ivS[455]), f3 = sigf(ivS[456]);
        float ret = (1.f-f0*lw4.x)*(1.f-f1*lw4.y)*(1.f-f2*lw4.z)*(1.f-f3*lw4.w);
        float uo = ubuf[b*1024+n], lwo = lww[b*1024+n];
        float un = (uo + lwo - uo*lwo)*ret;
        ubuf[b*1024+n] = un;

        unsigned long long key = ((unsigned long long)__float_as_uint(un) << 32) | (unsigned)tid;
        for (int k = 2; k <= 1024; k <<= 1){
            int j = k >> 1;
            for (; j >= 64; j >>= 1){
                keysS[tid] = key; __syncthreads();
                unsigned long long other = keysS[tid ^ j];
                bool up = ((tid & k) == 0);
                bool takeMin = (((tid & j) == 0) == up);
                key = takeMin ? (key < other ? key : other) : (key > other ? key : other);
                __syncthreads();
            }
            for (; j >= 1; j >>= 1){
                unsigned long long other = __shfl_xor(key, j);
                bool up = ((tid & k) == 0);
                bool takeMin = (((tid & j) == 0) == up);
                key = takeMin ? (key < other ? key : other) : (key > other ? key : other);
            }
        }
        float su = __uint_as_float((unsigned)(key >> 32));
        int idxv = (int)(key & 0xffffffffu);

        float p = su;
        #pragma unroll
        for (int o = 1; o < 64; o <<= 1){ float q = __shfl_up(p, o); if (lane >= o) p *= q; }
        if (lane == 63) wtot[wid] = p;
        __syncthreads();
        if (tid == 0){
            float r = 1.f;
            #pragma unroll
            for (int i = 0; i < 16; ++i){ wpref[i] = r; r *= wtot[i]; }
        }
        __syncthreads();
        float excl = __shfl_up(p, 1); if (lane == 0) excl = 1.f;
        float cpx = excl * wpref[wid];
        allocw[b*1024 + idxv] = (1.f - su)*cpx;
    } else {
        const int b = bid - 32;
        float myv = 0.f;
        if (tid < ET){
            #pragma unroll
            for (int s = 0; s < VKS; ++s) myv += ep[((size_t)s*BSZ + b)*ET + tid];
        }
        float mean = bsum(myv, red, tid) * (1.f/ET);
        float dd = (tid < ET) ? (myv - mean) : 0.f;
        float var = bsum(dd*dd, red, tid) * (1.f/ET);
        float rinv = 1.f / sqrtf(var + 1e-5f);
        float ivv = (myv - mean)*rinv;
        if (tid >= 260 && tid < 324) ivS[tid - 260] = ivv;   // write key
        if (tid == 324) ivS[64] = 1.f - logsigf(ivv);        // wbeta
        __syncthreads();
        float ksq = 0.f;
        #pragma unroll
        for (int w = 0; w < 64; ++w) ksq += ivS[w]*ivS[w];
        float kden = sqrtf(ksq) + 1e-8f;
        float wb = ivS[64];
        const float* Mrow = M + ((size_t)b*1024 + tid)*64;
        float dot = 0.f, msq = 0.f;
        #pragma unroll
        for (int w = 0; w < 64; w += 4){
            float4 mv = *(const float4*)(Mrow + w);
            dot += mv.x*ivS[w] + mv.y*ivS[w+1] + mv.z*ivS[w+2] + mv.w*ivS[w+3];
            msq += mv.x*mv.x + mv.y*mv.y + mv.z*mv.z + mv.w*mv.w;
        }
        scw[b*1024 + tid] = wb*dot/((sqrtf(msq) + 1e-8f)*kden);
    }
}

// ------- fused memory tail (32 blks x 1024): cw-softmax+ww, M update, read scores,
//         read softmax, read vectors (1x M re-read; rw via L1-hot lrw float4). --------
__global__ __launch_bounds__(1024) void dnc_memup_rv(
    float* __restrict__ M, const float* __restrict__ scw,
    const float* __restrict__ allocw, const float* __restrict__ iv,
    float* __restrict__ lww, float* __restrict__ lrw, float* __restrict__ lrv)
{
    const int b = blockIdx.x, tid = threadIdx.x;
    const int lane = tid & 63, wid = tid >> 6;
    __shared__ float red[32];
    __shared__ float aux[400];
    __shared__ float pS[4096];     // [r][n] scores
    __shared__ float rvS[4096];    // [r][g][w] partials
    const int n = tid;

    // ---- content-write softmax + ww ----
    float s = scw[b*1024 + n];
    float mx = bmax(s, red, tid);
    float tot = bsum(expf(s - mx), red, tid);
    float cwv = expf(s - mx)/tot;
    float ag = sigf(iv[b*ET + 457]), wg = sigf(iv[b*ET + 458]);
    float wwv = wg*(ag*allocw[b*1024 + n] + (1.f-ag)*cwv);
    lww[b*1024 + n] = wwv;

    // stage erase[0..63], wvec[64..127], rkn[128..383], nrm[384..387], rb[392..395]
    if (tid < 64){ aux[tid] = sigf(iv[b*ET + 325 + tid]); aux[64+tid] = iv[b*ET + 389 + tid]; }
    if (tid >= 64 && tid < 320) aux[64 + tid] = iv[b*ET + (tid - 64)];
    if (tid >= 320 && tid < 324) aux[72 + tid] = 1.f - logsigf(iv[b*ET + 256 + (tid - 320)]);
    __syncthreads();
    if (tid < 4){
        float ss = 0.f;
        #pragma unroll
        for (int w = 0; w < 64; ++w){ float v = aux[128 + w*4 + tid]; ss += v*v; }
        aux[384 + tid] = sqrtf(ss) + 1e-8f;
    }
    __syncthreads();
    if (tid < 256) aux[128 + tid] = aux[128 + tid] / aux[384 + (tid & 3)];
    __syncthreads();

    // ---- M update + read scores (scores -> LDS) ----
    float* Mrow = M + ((size_t)b*1024 + n)*64;
    float dr0=0.f, dr1=0.f, dr2=0.f, dr3=0.f, msq2=0.f;
    #pragma unroll
    for (int w = 0; w < 64; w += 4){
        float4 mv = *(const float4*)(Mrow + w);
        mv.x = mv.x*(1.f - wwv*aux[w+0]) + wwv*aux[64+w+0];
        mv.y = mv.y*(1.f - wwv*aux[w+1]) + wwv*aux[64+w+1];
        mv.z = mv.z*(1.f - wwv*aux[w+2]) + wwv*aux[64+w+2];
        mv.w = mv.w*(1.f - wwv*aux[w+3]) + wwv*aux[64+w+3];
        *(float4*)(Mrow + w) = mv;
        msq2 += mv.x*mv.x + mv.y*mv.y + mv.z*mv.z + mv.w*mv.w;
        dr0 += mv.x*aux[128+(w+0)*4+0] + mv.y*aux[128+(w+1)*4+0] + mv.z*aux[128+(w+2)*4+0] + mv.w*aux[128+(w+3)*4+0];
        dr1 += mv.x*aux[128+(w+0)*4+1] + mv.y*aux[128+(w+1)*4+1] + mv.z*aux[128+(w+2)*4+1] + mv.w*aux[128+(w+3)*4+1];
        dr2 += mv.x*aux[128+(w+0)*4+2] + mv.y*aux[128+(w+1)*4+2] + mv.z*aux[128+(w+2)*4+2] + mv.w*aux[128+(w+3)*4+2];
        dr3 += mv.x*aux[128+(w+0)*4+3] + mv.y*aux[128+(w+1)*4+3] + mv.z*aux[128+(w+2)*4+3] + mv.w*aux[128+(w+3)*4+3];
    }
    float den = sqrtf(msq2) + 1e-8f;
    pS[0*1024 + n] = aux[392]*dr0/den;
    pS[1*1024 + n] = aux[393]*dr1/den;
    pS[2*1024 + n] = aux[394]*dr2/den;
    pS[3*1024 + n] = aux[395]*dr3/den;
    __syncthreads();

    // ---- read softmax per r (r_ = tid>>8 owns 4 n); writes lrw [n][4] ----
    const int r_ = tid >> 8, i4 = (tid & 255)*4;
    float v0 = pS[r_*1024 + i4+0], v1 = pS[r_*1024 + i4+1];
    float v2 = pS[r_*1024 + i4+2], v3 = pS[r_*1024 + i4+3];
    float lm = fmaxf(fmaxf(v0,v1), fmaxf(v2,v3));
    #pragma unroll
    for (int off = 32; off > 0; off >>= 1) lm = fmaxf(lm, __shfl_xor(lm, off));
    if (lane == 0) red[wid] = lm;
    __syncthreads();
    if (tid < 4) red[16+tid] = fmaxf(fmaxf(red[4*tid],red[4*tid+1]), fmaxf(red[4*tid+2],red[4*tid+3]));
    __syncthreads();
    float mxr = red[16 + r_];
    float lsum = expf(v0-mxr) + expf(v1-mxr) + expf(v2-mxr) + expf(v3-mxr);
    #pragma unroll
    for (int off = 32; off > 0; off >>= 1) lsum += __shfl_xor(lsum, off);
    if (lane == 0) red[wid] = lsum;
    __syncthreads();
    if (tid < 4) red[20+tid] = red[4*tid]+red[4*tid+1]+red[4*tid+2]+red[4*tid+3];
    __syncthreads();
    float totr = red[20 + r_];
    {
        lrw[((size_t)(b*1024 + i4+0))*4 + r_] = expf(v0-mxr)/totr;
        lrw[((size_t)(b*1024 + i4+1))*4 + r_] = expf(v1-mxr)/totr;
        lrw[((size_t)(b*1024 + i4+2))*4 + r_] = expf(v2-mxr)/totr;
        lrw[((size_t)(b*1024 + i4+3))*4 + r_] = expf(v3-mxr)/totr;
    }
    __syncthreads();

    // ---- read vectors: thread (g = tid>>6 row-group, w = tid&63); 1x M reads ----
    {
        const int w = tid & 63, g = tid >> 6;
        const float* Mb = M + (size_t)b*65536;
        const float* rwb = lrw + (size_t)b*4096;
        float a0=0.f, a1=0.f, a2=0.f, a3=0.f;
        #pragma unroll 4
        for (int i = 0; i < 64; ++i){
            int n2 = g*64 + i;
            float m = Mb[(size_t)n2*64 + w];
            float4 rw4 = *(const float4*)&rwb[n2*4];
            a0 += m*rw4.x; a1 += m*rw4.y; a2 += m*rw4.z; a3 += m*rw4.w;
        }
        rvS[(0*16 + g)*64 + w] = a0;
        rvS[(1*16 + g)*64 + w] = a1;
        rvS[(2*16 + g)*64 + w] = a2;
        rvS[(3*16 + g)*64 + w] = a3;
    }
    __syncthreads();
    if (tid < 256){
        int w2 = tid >> 2, r2 = tid & 3;
        float ssum = 0.f;
        #pragma unroll
        for (int g = 0; g < 16; ++g) ssum += rvS[(r2*16 + g)*64 + w2];
        lrv[b*256 + tid] = ssum;     // layout [b][w*4+r]
    }
}

extern "C" void kernel_launch(void* const* d_in, const int* in_sizes, int n_in,
                              void* d_out, int out_size, void* d_ws, size_t ws_size,
                              hipStream_t stream){
    const float* x      = (const float*)d_in[0];
    const float* mem0   = (const float*)d_in[1];
    const float* Wy     = (const float*)d_in[2];
    const float* WE     = (const float*)d_in[3];
    const float* Wr     = (const float*)d_in[4];
    const float* Wih0   = (const float*)d_in[5];
    const float* Whh0   = (const float*)d_in[6];
    const float* bih0   = (const float*)d_in[7];
    const float* bhh0   = (const float*)d_in[8];
    const float* Wih1   = (const float*)d_in[9];
    const float* Whh1   = (const float*)d_in[10];
    const float* bih1   = (const float*)d_in[11];
    const float* bhh1   = (const float*)d_in[12];
    float* out = (float*)d_out;

    float* p = (float*)d_ws;
    float* M       = p; p += (size_t)BSZ*1024*64;
    float* hstate0 = p; p += 4*BSZ*HD;     // zero block start
    float* hstate1 = p; p += 4*BSZ*HD;
    float* cstate  = p; p += 4*BSZ*HD;
    float* ubuf    = p; p += BSZ*1024;
    float* lww     = p; p += BSZ*1024;
    float* lrw     = p; p += BSZ*1024*4;
    float* lrv     = p; p += BSZ*256;      // zero block end
    float* bnx     = p; p += (size_t)TT*BSZ*XD;
    float* lin1    = p; p += BSZ*1024;
    float* gpart   = p; p += (size_t)2*GKS*BSZ*2048;
    float* flat    = p; p += BSZ*2048;
    float* vtp     = p; p += (size_t)VKS*BSZ*VT;
    float* ep      = p; p += (size_t)VKS*BSZ*ET;
    float* iv      = p; p += BSZ*ET;
    float* allocw  = p; p += BSZ*1024;
    float* scw     = p; p += BSZ*1024;

    (void)hipMemcpyAsync(M, mem0, (size_t)BSZ*1024*64*sizeof(float), hipMemcpyDeviceToDevice, stream);
    size_t zfloats = (size_t)(4*BSZ*HD)*3 + BSZ*1024*2 + BSZ*1024*4 + BSZ*256;
    (void)hipMemsetAsync(hstate0, 0, zfloats*sizeof(float), stream);

    dnc_bnx<<<TT, 128, 0, stream>>>(x, bnx);

    for (int t = 0; t < TT; ++t){
        const float* hr = (t & 1) ? hstate1 : hstate0;
        float*       hw = (t & 1) ? hstate0 : hstate1;
        dnc_gemm0_yfin<<<320, 256, 0, stream>>>(bnx + (size_t)t*BSZ*XD,
            lrv, hr, Wih0, Whh0, gpart, Wr, vtp, out, t - 1);
        dnc_gates<<<128, 256, 0, stream>>>(gpart, bih0, bhh0, cstate, hw, flat, lin1, 0);
        dnc_lstm_gemm<<<dim3(16,2,GKS), 256, 0, stream>>>(lin1, 1024,
            nullptr, 0, hr + 2*BSZ*HD, Wih1, Whh1, gpart);
        dnc_gates<<<128, 256, 0, stream>>>(gpart, bih1, bhh1, cstate, hw, flat, nullptr, 1);
        dnc_gemv2<<<dim3(12,VKS), 256, 0, stream>>>(flat, Wy, WE, vtp, ep);
        dnc_presort_cw<<<64, 1024, 0, stream>>>(ep, lrw, lww, ubuf, iv, allocw, M, scw);
        dnc_memup_rv<<<32, 1024, 0, stream>>>(M, scw, allocw, iv, lww, lrw, lrv);
    }
    dnc_yfin<<<dim3(16,4), 256, 0, stream>>>(lrv, Wr, vtp, out, TT - 1);
}